// Round 1
// baseline (529.920 us; speedup 1.0000x reference)
//
#include <hip/hip_runtime.h>

#define N_NODES 50000
#define N_EDGES 800000
#define C_IN 128
#define C_HID 256
#define C_OUT 128
#define BN_EPS 1e-5f

// ---------------- degree / normalization ----------------

__global__ __launch_bounds__(256) void k_deg(const int* __restrict__ dst, int* __restrict__ deg) {
    int e = blockIdx.x * 256 + threadIdx.x;
    if (e < N_EDGES) atomicAdd(&deg[dst[e]], 1);
}

__global__ __launch_bounds__(256) void k_dis(const int* __restrict__ deg, float* __restrict__ dis) {
    int i = blockIdx.x * 256 + threadIdx.x;
    if (i < N_NODES) dis[i] = rsqrtf((float)deg[i] + 1.0f);
}

// ---------------- CSR build: scan + scatter ----------------

__global__ __launch_bounds__(512) void k_scan1(const int* __restrict__ deg, int* __restrict__ rs,
                                               int* __restrict__ partial) {
    __shared__ int s[512];
    int t = threadIdx.x;
    int i = blockIdx.x * 512 + t;
    s[t] = (i < N_NODES) ? deg[i] : 0;
    __syncthreads();
    for (int off = 1; off < 512; off <<= 1) {
        int tv = (t >= off) ? s[t - off] : 0;
        __syncthreads();
        s[t] += tv;
        __syncthreads();
    }
    if (i < N_NODES) rs[i + 1] = s[t];
    if (t == 511) partial[blockIdx.x] = s[511];
}

__global__ void k_scan2(const int* __restrict__ partial, int* __restrict__ poff, int nb) {
    if (threadIdx.x == 0) {
        int run = 0;
        for (int b = 0; b < nb; ++b) { poff[b] = run; run += partial[b]; }
    }
}

__global__ __launch_bounds__(256) void k_scan3(int* __restrict__ rs, const int* __restrict__ poff) {
    int i = blockIdx.x * 256 + threadIdx.x;
    if (i < N_NODES) rs[i + 1] += poff[i >> 9];
    if (i == 0) rs[0] = 0;
}

__global__ __launch_bounds__(256) void k_cursor(const int* __restrict__ rs, int* __restrict__ cur) {
    int i = blockIdx.x * 256 + threadIdx.x;
    if (i < N_NODES) cur[i] = rs[i];
}

__global__ __launch_bounds__(256) void k_scatter(const int* __restrict__ src, const int* __restrict__ dst,
                                                 int* __restrict__ cur, int* __restrict__ eidx) {
    int e = blockIdx.x * 256 + threadIdx.x;
    if (e < N_EDGES) {
        int pos = atomicAdd(&cur[dst[e]], 1);
        eidx[pos] = src[e];
    }
}

// ---------------- tiled fp32 GEMM: C[r][c] = (sum_k A[r][k]*B[k][c]) * dis[r] ----------------
// TRANS: A-load transform y = relu(a*tsc[k] + tof[k])  (fused BN+ReLU for layer 2)

#define BM 64
#define BN 64
#define BK 16

template <bool TRANS>
__global__ __launch_bounds__(256) void k_gemm(const float* __restrict__ A, const float* __restrict__ B,
                                              float* __restrict__ C, const float* __restrict__ dis,
                                              const float* __restrict__ tsc, const float* __restrict__ tof,
                                              int M, int N, int K) {
    __shared__ float As[BK][68];   // +4 pad: 16B-aligned rows, conflict-spread scalar writes
    __shared__ float Ws[BK][BN];
    int tid = threadIdx.x;
    int row0 = blockIdx.x * BM;
    int col0 = blockIdx.y * BN;
    int tx = tid & 15, ty = tid >> 4;
    int arow = row0 + (tid >> 2);
    int acol4 = (tid & 3) * 4;
    int wrow = tid >> 4;
    int wcol4 = (tid & 15) * 4;
    float acc[4][4] = {};

    for (int kt = 0; kt < K; kt += BK) {
        float4 av = make_float4(0.f, 0.f, 0.f, 0.f);
        if (arow < M) {
            av = *(const float4*)&A[(size_t)arow * K + kt + acol4];
            if (TRANS) {
                float4 s4 = *(const float4*)&tsc[kt + acol4];
                float4 o4 = *(const float4*)&tof[kt + acol4];
                av.x = fmaxf(fmaf(av.x, s4.x, o4.x), 0.f);
                av.y = fmaxf(fmaf(av.y, s4.y, o4.y), 0.f);
                av.z = fmaxf(fmaf(av.z, s4.z, o4.z), 0.f);
                av.w = fmaxf(fmaf(av.w, s4.w, o4.w), 0.f);
            }
        }
        float4 wv = *(const float4*)&B[(size_t)(kt + wrow) * N + col0 + wcol4];
        __syncthreads();  // previous tile's reads complete
        As[acol4 + 0][tid >> 2] = av.x;
        As[acol4 + 1][tid >> 2] = av.y;
        As[acol4 + 2][tid >> 2] = av.z;
        As[acol4 + 3][tid >> 2] = av.w;
        *(float4*)&Ws[wrow][wcol4] = wv;
        __syncthreads();
#pragma unroll
        for (int k = 0; k < BK; ++k) {
            float ar[4], br[4];
            *(float4*)ar = *(const float4*)&As[k][ty * 4];
            *(float4*)br = *(const float4*)&Ws[k][tx * 4];
#pragma unroll
            for (int i = 0; i < 4; ++i)
#pragma unroll
                for (int j = 0; j < 4; ++j) acc[i][j] = fmaf(ar[i], br[j], acc[i][j]);
        }
    }
#pragma unroll
    for (int i = 0; i < 4; ++i) {
        int r = row0 + ty * 4 + i;
        if (r < M) {
            float d = dis[r];
            float4 o = make_float4(acc[i][0] * d, acc[i][1] * d, acc[i][2] * d, acc[i][3] * d);
            *(float4*)&C[(size_t)r * N + col0 + tx * 4] = o;
        }
    }
}

// ---------------- aggregation: one wave per node ----------------
// z1[i] = dis[i] * (sum_{src->i} g1[src] + g1[i]) + b1     (256 ch: float4/lane)

__global__ __launch_bounds__(256) void k_agg1(const float* __restrict__ g1, const float* __restrict__ dis,
                                              const float* __restrict__ b1, const int* __restrict__ rs,
                                              const int* __restrict__ eidx, float* __restrict__ z1) {
    int wid = (blockIdx.x * 256 + threadIdx.x) >> 6;
    int lane = threadIdx.x & 63;
    if (wid >= N_NODES) return;
    int s = rs[wid], e = rs[wid + 1];
    float4 acc = make_float4(0.f, 0.f, 0.f, 0.f);
    int p = s;
    for (; p + 1 < e; p += 2) {
        int s0 = eidx[p], s1 = eidx[p + 1];
        float4 v0 = *(const float4*)&g1[(size_t)s0 * C_HID + lane * 4];
        float4 v1 = *(const float4*)&g1[(size_t)s1 * C_HID + lane * 4];
        acc.x += v0.x + v1.x; acc.y += v0.y + v1.y;
        acc.z += v0.z + v1.z; acc.w += v0.w + v1.w;
    }
    if (p < e) {
        int s0 = eidx[p];
        float4 v0 = *(const float4*)&g1[(size_t)s0 * C_HID + lane * 4];
        acc.x += v0.x; acc.y += v0.y; acc.z += v0.z; acc.w += v0.w;
    }
    float4 gi = *(const float4*)&g1[(size_t)wid * C_HID + lane * 4];
    float d = dis[wid];
    float4 bv = *(const float4*)&b1[lane * 4];
    float4 z = make_float4(fmaf(d, acc.x + gi.x, bv.x), fmaf(d, acc.y + gi.y, bv.y),
                           fmaf(d, acc.z + gi.z, bv.z), fmaf(d, acc.w + gi.w, bv.w));
    *(float4*)&z1[(size_t)wid * C_HID + lane * 4] = z;
}

// out[i] = dis[i] * (sum g2[src] + g2[i]) + b2      (128 ch: float2/lane)
__global__ __launch_bounds__(256) void k_agg2(const float* __restrict__ g2, const float* __restrict__ dis,
                                              const float* __restrict__ b2, const int* __restrict__ rs,
                                              const int* __restrict__ eidx, float* __restrict__ out) {
    int wid = (blockIdx.x * 256 + threadIdx.x) >> 6;
    int lane = threadIdx.x & 63;
    if (wid >= N_NODES) return;
    int s = rs[wid], e = rs[wid + 1];
    float2 acc = make_float2(0.f, 0.f);
    int p = s;
    for (; p + 1 < e; p += 2) {
        int s0 = eidx[p], s1 = eidx[p + 1];
        float2 v0 = *(const float2*)&g2[(size_t)s0 * C_OUT + lane * 2];
        float2 v1 = *(const float2*)&g2[(size_t)s1 * C_OUT + lane * 2];
        acc.x += v0.x + v1.x; acc.y += v0.y + v1.y;
    }
    if (p < e) {
        int s0 = eidx[p];
        float2 v0 = *(const float2*)&g2[(size_t)s0 * C_OUT + lane * 2];
        acc.x += v0.x; acc.y += v0.y;
    }
    float2 gi = *(const float2*)&g2[(size_t)wid * C_OUT + lane * 2];
    float d = dis[wid];
    float2 bv = *(const float2*)&b2[lane * 2];
    float2 o = make_float2(fmaf(d, acc.x + gi.x, bv.x), fmaf(d, acc.y + gi.y, bv.y));
    *(float2*)&out[(size_t)wid * C_OUT + lane * 2] = o;
}

// ---------------- BN stats ----------------

__global__ __launch_bounds__(256) void k_bnstats(const float* __restrict__ z1, float* __restrict__ bnsum,
                                                 float* __restrict__ bnsq) {
    int c = threadIdx.x;
    int r0 = blockIdx.x * 256;
    int r1 = r0 + 256 < N_NODES ? r0 + 256 : N_NODES;
    float sum = 0.f, sq = 0.f;
    for (int r = r0; r < r1; ++r) {
        float v = z1[(size_t)r * C_HID + c];
        sum += v;
        sq = fmaf(v, v, sq);
    }
    atomicAdd(&bnsum[c], sum);
    atomicAdd(&bnsq[c], sq);
}

__global__ void k_bnfinal(const float* __restrict__ bnsum, const float* __restrict__ bnsq,
                          const float* __restrict__ gamma, const float* __restrict__ beta,
                          float* __restrict__ a_c, float* __restrict__ b_c) {
    int c = threadIdx.x;
    float inv_n = 1.0f / (float)N_NODES;
    float mu = bnsum[c] * inv_n;
    float var = bnsq[c] * inv_n - mu * mu;
    float a = gamma[c] * rsqrtf(var + BN_EPS);
    a_c[c] = a;
    b_c[c] = beta[c] - mu * a;
}

// ---------------- launch ----------------

extern "C" void kernel_launch(void* const* d_in, const int* in_sizes, int n_in,
                              void* d_out, int out_size, void* d_ws, size_t ws_size,
                              hipStream_t stream) {
    const float* x      = (const float*)d_in[0];
    const int*   ei     = (const int*)d_in[1];
    const float* W1     = (const float*)d_in[2];
    const float* b1     = (const float*)d_in[3];
    const float* gamma1 = (const float*)d_in[4];
    const float* beta1  = (const float*)d_in[5];
    const float* W2     = (const float*)d_in[6];
    const float* b2     = (const float*)d_in[7];
    const int* srcv = ei;
    const int* dstv = ei + N_EDGES;
    float* out = (float*)d_out;

    char* w = (char*)d_ws;
    size_t off = 0;
    auto alloc = [&](size_t bytes) {
        void* p = w + off;
        off = (off + bytes + 255) & ~(size_t)255;
        return p;
    };
    int*   deg     = (int*)alloc(N_NODES * 4);
    float* dis     = (float*)alloc(N_NODES * 4);
    int*   rs      = (int*)alloc((N_NODES + 1) * 4);
    int*   cur     = (int*)alloc(N_NODES * 4);
    int*   partial = (int*)alloc(128 * 4);
    int*   poff    = (int*)alloc(128 * 4);
    float* bnsum   = (float*)alloc(256 * 4);
    float* bnsq    = (float*)alloc(256 * 4);
    float* a_c     = (float*)alloc(256 * 4);
    float* b_c     = (float*)alloc(256 * 4);
    int*   eidx    = (int*)alloc((size_t)N_EDGES * 4);
    float* g1      = (float*)alloc((size_t)N_NODES * C_HID * 4);
    float* z1      = (float*)alloc((size_t)N_NODES * C_HID * 4);
    float* g2      = (float*)alloc((size_t)N_NODES * C_OUT * 4);
    (void)ws_size; (void)in_sizes; (void)n_in; (void)out_size;

    hipMemsetAsync(deg, 0, N_NODES * 4, stream);
    hipMemsetAsync(bnsum, 0, 2048, stream);  // bnsum + bnsq (contiguous, 256B-aligned blocks)

    int nb = (N_NODES + 511) / 512;  // 98
    k_deg<<<(N_EDGES + 255) / 256, 256, 0, stream>>>(dstv, deg);
    k_dis<<<(N_NODES + 255) / 256, 256, 0, stream>>>(deg, dis);
    k_scan1<<<nb, 512, 0, stream>>>(deg, rs, partial);
    k_scan2<<<1, 64, 0, stream>>>(partial, poff, nb);
    k_scan3<<<(N_NODES + 255) / 256, 256, 0, stream>>>(rs, poff);
    k_cursor<<<(N_NODES + 255) / 256, 256, 0, stream>>>(rs, cur);
    k_scatter<<<(N_EDGES + 255) / 256, 256, 0, stream>>>(srcv, dstv, cur, eidx);

    dim3 gg1((N_NODES + BM - 1) / BM, C_HID / BN);
    k_gemm<false><<<gg1, 256, 0, stream>>>(x, W1, g1, dis, nullptr, nullptr, N_NODES, C_HID, C_IN);
    k_agg1<<<(N_NODES * 64 + 255) / 256, 256, 0, stream>>>(g1, dis, b1, rs, eidx, z1);
    k_bnstats<<<(N_NODES + 255) / 256, 256, 0, stream>>>(z1, bnsum, bnsq);
    k_bnfinal<<<1, 256, 0, stream>>>(bnsum, bnsq, gamma1, beta1, a_c, b_c);

    dim3 gg2((N_NODES + BM - 1) / BM, C_OUT / BN);
    k_gemm<true><<<gg2, 256, 0, stream>>>(z1, W2, g2, dis, a_c, b_c, N_NODES, C_OUT, C_HID);
    k_agg2<<<(N_NODES * 64 + 255) / 256, 256, 0, stream>>>(g2, dis, b2, rs, eidx, out);
}

// Round 2
// 473.692 us; speedup vs baseline: 1.1187x; 1.1187x over previous
//
#include <hip/hip_runtime.h>

#define N_NODES 50000
#define N_EDGES 800000
#define C_IN 128
#define C_HID 256
#define C_OUT 128
#define BN_EPS 1e-5f

// ---------- bf16 helpers (round-to-nearest-even) ----------
static __device__ __forceinline__ unsigned short f2bf(float f) {
    unsigned int u = __float_as_uint(f);
    u += 0x7fffu + ((u >> 16) & 1u);
    return (unsigned short)(u >> 16);
}
static __device__ __forceinline__ float bf2f(unsigned short h) {
    return __uint_as_float((unsigned int)h << 16);
}

// ---------------- degree / normalization ----------------

__global__ __launch_bounds__(256) void k_deg(const int* __restrict__ dst, int* __restrict__ deg) {
    int e = blockIdx.x * 256 + threadIdx.x;
    if (e < N_EDGES) atomicAdd(&deg[dst[e]], 1);
}

__global__ __launch_bounds__(256) void k_dis(const int* __restrict__ deg, float* __restrict__ dis) {
    int i = blockIdx.x * 256 + threadIdx.x;
    if (i < N_NODES) dis[i] = rsqrtf((float)deg[i] + 1.0f);
}

// ---------------- CSR build: scan + scatter ----------------

__global__ __launch_bounds__(512) void k_scan1(const int* __restrict__ deg, int* __restrict__ rs,
                                               int* __restrict__ partial) {
    __shared__ int s[512];
    int t = threadIdx.x;
    int i = blockIdx.x * 512 + t;
    s[t] = (i < N_NODES) ? deg[i] : 0;
    __syncthreads();
    for (int off = 1; off < 512; off <<= 1) {
        int tv = (t >= off) ? s[t - off] : 0;
        __syncthreads();
        s[t] += tv;
        __syncthreads();
    }
    if (i < N_NODES) rs[i + 1] = s[t];
    if (t == 511) partial[blockIdx.x] = s[511];
}

__global__ void k_scan2(const int* __restrict__ partial, int* __restrict__ poff, int nb) {
    if (threadIdx.x == 0) {
        int run = 0;
        for (int b = 0; b < nb; ++b) { poff[b] = run; run += partial[b]; }
    }
}

__global__ __launch_bounds__(256) void k_scan3(int* __restrict__ rs, const int* __restrict__ poff) {
    int i = blockIdx.x * 256 + threadIdx.x;
    if (i < N_NODES) rs[i + 1] += poff[i >> 9];
    if (i == 0) rs[0] = 0;
}

__global__ __launch_bounds__(256) void k_cursor(const int* __restrict__ rs, int* __restrict__ cur) {
    int i = blockIdx.x * 256 + threadIdx.x;
    if (i < N_NODES) cur[i] = rs[i];
}

__global__ __launch_bounds__(256) void k_scatter(const int* __restrict__ src, const int* __restrict__ dst,
                                                 int* __restrict__ cur, int* __restrict__ eidx) {
    int e = blockIdx.x * 256 + threadIdx.x;
    if (e < N_EDGES) {
        int pos = atomicAdd(&cur[dst[e]], 1);
        eidx[pos] = src[e];
    }
}

// ---------------- tiled fp32 GEMM -> bf16 out: C[r][c] = bf16( (A@B)[r][c] * dis[r] ) ----
// TRANS: A is bf16 with fused BN+ReLU transform y = relu(a*tsc[k] + tof[k]).
// BM=128, BN=64, BK=16, 256 threads, TM=8 x TN=4 per thread:
//   32 FMA : 3 ds_read_b128 per k-step (vs 16:2 in the 64x64 tile).

#define BM 128
#define BN 64
#define BK 16

template <bool TRANS>
__global__ __launch_bounds__(256) void k_gemm(const void* __restrict__ Av, const float* __restrict__ B,
                                              unsigned short* __restrict__ C, const float* __restrict__ dis,
                                              const float* __restrict__ tsc, const float* __restrict__ tof,
                                              int M, int N, int K) {
    __shared__ float As[BK][BM + 4];   // transposed A tile; +4 keeps rows 16B-aligned
    __shared__ float Ws[BK][BN];
    int tid = threadIdx.x;
    int row0 = blockIdx.x * BM;
    int col0 = blockIdx.y * BN;
    int tx = tid & 15, ty = tid >> 4;      // 16 x 16 thread layout
    int ar0 = tid >> 2;                    // 0..63 (A staging row, +64 for second)
    int acol4 = (tid & 3) * 4;             // 0,4,8,12
    int wrow = tid >> 4;                   // 0..15
    int wcol4 = (tid & 15) * 4;            // 0..60
    float acc[8][4] = {};

    const float* Af = (const float*)Av;
    const unsigned short* Ah = (const unsigned short*)Av;

    for (int kt = 0; kt < K; kt += BK) {
        float a0[4] = {0.f, 0.f, 0.f, 0.f}, a1[4] = {0.f, 0.f, 0.f, 0.f};
        int r0 = row0 + ar0, r1 = row0 + ar0 + 64;
        if (TRANS) {
            float s4[4], o4[4];
            *(float4*)s4 = *(const float4*)&tsc[kt + acol4];
            *(float4*)o4 = *(const float4*)&tof[kt + acol4];
            if (r0 < M) {
                ushort4 h = *(const ushort4*)&Ah[(size_t)r0 * K + kt + acol4];
                a0[0] = fmaxf(fmaf(bf2f(h.x), s4[0], o4[0]), 0.f);
                a0[1] = fmaxf(fmaf(bf2f(h.y), s4[1], o4[1]), 0.f);
                a0[2] = fmaxf(fmaf(bf2f(h.z), s4[2], o4[2]), 0.f);
                a0[3] = fmaxf(fmaf(bf2f(h.w), s4[3], o4[3]), 0.f);
            }
            if (r1 < M) {
                ushort4 h = *(const ushort4*)&Ah[(size_t)r1 * K + kt + acol4];
                a1[0] = fmaxf(fmaf(bf2f(h.x), s4[0], o4[0]), 0.f);
                a1[1] = fmaxf(fmaf(bf2f(h.y), s4[1], o4[1]), 0.f);
                a1[2] = fmaxf(fmaf(bf2f(h.z), s4[2], o4[2]), 0.f);
                a1[3] = fmaxf(fmaf(bf2f(h.w), s4[3], o4[3]), 0.f);
            }
        } else {
            if (r0 < M) *(float4*)a0 = *(const float4*)&Af[(size_t)r0 * K + kt + acol4];
            if (r1 < M) *(float4*)a1 = *(const float4*)&Af[(size_t)r1 * K + kt + acol4];
        }
        float4 wv = *(const float4*)&B[(size_t)(kt + wrow) * N + col0 + wcol4];
        __syncthreads();  // previous tile's LDS reads complete
        As[acol4 + 0][ar0] = a0[0];
        As[acol4 + 1][ar0] = a0[1];
        As[acol4 + 2][ar0] = a0[2];
        As[acol4 + 3][ar0] = a0[3];
        As[acol4 + 0][ar0 + 64] = a1[0];
        As[acol4 + 1][ar0 + 64] = a1[1];
        As[acol4 + 2][ar0 + 64] = a1[2];
        As[acol4 + 3][ar0 + 64] = a1[3];
        *(float4*)&Ws[wrow][wcol4] = wv;
        __syncthreads();
#pragma unroll
        for (int k = 0; k < BK; ++k) {
            float ar[8], br[4];
            *(float4*)&ar[0] = *(const float4*)&As[k][ty * 8];
            *(float4*)&ar[4] = *(const float4*)&As[k][ty * 8 + 4];
            *(float4*)&br[0] = *(const float4*)&Ws[k][tx * 4];
#pragma unroll
            for (int i = 0; i < 8; ++i)
#pragma unroll
                for (int j = 0; j < 4; ++j) acc[i][j] = fmaf(ar[i], br[j], acc[i][j]);
        }
    }
#pragma unroll
    for (int i = 0; i < 8; ++i) {
        int r = row0 + ty * 8 + i;
        if (r < M) {
            float d = dis[r];
            ushort4 o;
            o.x = f2bf(acc[i][0] * d);
            o.y = f2bf(acc[i][1] * d);
            o.z = f2bf(acc[i][2] * d);
            o.w = f2bf(acc[i][3] * d);
            *(ushort4*)&C[(size_t)r * N + col0 + tx * 4] = o;
        }
    }
}

// ---------------- aggregation: one wave per node (bf16 rows, fp32 accumulate) ----------------
// z1[i] = bf16( dis[i] * (sum_{src->i} g1[src] + g1[i]) + b1 )   (256 ch: ushort4/lane = 512B/row)

__global__ __launch_bounds__(256) void k_agg1(const unsigned short* __restrict__ g1, const float* __restrict__ dis,
                                              const float* __restrict__ b1, const int* __restrict__ rs,
                                              const int* __restrict__ eidx, unsigned short* __restrict__ z1) {
    int wid = (blockIdx.x * 256 + threadIdx.x) >> 6;
    int lane = threadIdx.x & 63;
    if (wid >= N_NODES) return;
    int s = rs[wid], e = rs[wid + 1];
    float ax = 0.f, ay = 0.f, az = 0.f, aw = 0.f;
    int p = s;
    for (; p + 1 < e; p += 2) {
        int s0 = eidx[p], s1 = eidx[p + 1];
        ushort4 v0 = *(const ushort4*)&g1[(size_t)s0 * C_HID + lane * 4];
        ushort4 v1 = *(const ushort4*)&g1[(size_t)s1 * C_HID + lane * 4];
        ax += bf2f(v0.x) + bf2f(v1.x);
        ay += bf2f(v0.y) + bf2f(v1.y);
        az += bf2f(v0.z) + bf2f(v1.z);
        aw += bf2f(v0.w) + bf2f(v1.w);
    }
    if (p < e) {
        int s0 = eidx[p];
        ushort4 v0 = *(const ushort4*)&g1[(size_t)s0 * C_HID + lane * 4];
        ax += bf2f(v0.x); ay += bf2f(v0.y); az += bf2f(v0.z); aw += bf2f(v0.w);
    }
    ushort4 gi = *(const ushort4*)&g1[(size_t)wid * C_HID + lane * 4];
    float d = dis[wid];
    float4 bv = *(const float4*)&b1[lane * 4];
    ushort4 z;
    z.x = f2bf(fmaf(d, ax + bf2f(gi.x), bv.x));
    z.y = f2bf(fmaf(d, ay + bf2f(gi.y), bv.y));
    z.z = f2bf(fmaf(d, az + bf2f(gi.z), bv.z));
    z.w = f2bf(fmaf(d, aw + bf2f(gi.w), bv.w));
    *(ushort4*)&z1[(size_t)wid * C_HID + lane * 4] = z;
}

// out[i] = dis[i] * (sum g2[src] + g2[i]) + b2      (128 ch: ushort2/lane = 256B/row, fp32 out)
__global__ __launch_bounds__(256) void k_agg2(const unsigned short* __restrict__ g2, const float* __restrict__ dis,
                                              const float* __restrict__ b2, const int* __restrict__ rs,
                                              const int* __restrict__ eidx, float* __restrict__ out) {
    int wid = (blockIdx.x * 256 + threadIdx.x) >> 6;
    int lane = threadIdx.x & 63;
    if (wid >= N_NODES) return;
    int s = rs[wid], e = rs[wid + 1];
    float ax = 0.f, ay = 0.f;
    int p = s;
    for (; p + 3 < e; p += 4) {
        int s0 = eidx[p], s1 = eidx[p + 1], s2 = eidx[p + 2], s3 = eidx[p + 3];
        ushort2 v0 = *(const ushort2*)&g2[(size_t)s0 * C_OUT + lane * 2];
        ushort2 v1 = *(const ushort2*)&g2[(size_t)s1 * C_OUT + lane * 2];
        ushort2 v2 = *(const ushort2*)&g2[(size_t)s2 * C_OUT + lane * 2];
        ushort2 v3 = *(const ushort2*)&g2[(size_t)s3 * C_OUT + lane * 2];
        ax += (bf2f(v0.x) + bf2f(v1.x)) + (bf2f(v2.x) + bf2f(v3.x));
        ay += (bf2f(v0.y) + bf2f(v1.y)) + (bf2f(v2.y) + bf2f(v3.y));
    }
    for (; p < e; ++p) {
        int s0 = eidx[p];
        ushort2 v0 = *(const ushort2*)&g2[(size_t)s0 * C_OUT + lane * 2];
        ax += bf2f(v0.x); ay += bf2f(v0.y);
    }
    ushort2 gi = *(const ushort2*)&g2[(size_t)wid * C_OUT + lane * 2];
    float d = dis[wid];
    float2 bv = *(const float2*)&b2[lane * 2];
    float2 o = make_float2(fmaf(d, ax + bf2f(gi.x), bv.x), fmaf(d, ay + bf2f(gi.y), bv.y));
    *(float2*)&out[(size_t)wid * C_OUT + lane * 2] = o;
}

// ---------------- BN stats (from bf16 z1) ----------------

__global__ __launch_bounds__(256) void k_bnstats(const unsigned short* __restrict__ z1, float* __restrict__ bnsum,
                                                 float* __restrict__ bnsq) {
    int c = threadIdx.x;
    int r0 = blockIdx.x * 256;
    int r1 = r0 + 256 < N_NODES ? r0 + 256 : N_NODES;
    float sum = 0.f, sq = 0.f;
    for (int r = r0; r < r1; ++r) {
        float v = bf2f(z1[(size_t)r * C_HID + c]);
        sum += v;
        sq = fmaf(v, v, sq);
    }
    atomicAdd(&bnsum[c], sum);
    atomicAdd(&bnsq[c], sq);
}

__global__ void k_bnfinal(const float* __restrict__ bnsum, const float* __restrict__ bnsq,
                          const float* __restrict__ gamma, const float* __restrict__ beta,
                          float* __restrict__ a_c, float* __restrict__ b_c) {
    int c = threadIdx.x;
    float inv_n = 1.0f / (float)N_NODES;
    float mu = bnsum[c] * inv_n;
    float var = bnsq[c] * inv_n - mu * mu;
    float a = gamma[c] * rsqrtf(var + BN_EPS);
    a_c[c] = a;
    b_c[c] = beta[c] - mu * a;
}

// ---------------- launch ----------------

extern "C" void kernel_launch(void* const* d_in, const int* in_sizes, int n_in,
                              void* d_out, int out_size, void* d_ws, size_t ws_size,
                              hipStream_t stream) {
    const float* x      = (const float*)d_in[0];
    const int*   ei     = (const int*)d_in[1];
    const float* W1     = (const float*)d_in[2];
    const float* b1     = (const float*)d_in[3];
    const float* gamma1 = (const float*)d_in[4];
    const float* beta1  = (const float*)d_in[5];
    const float* W2     = (const float*)d_in[6];
    const float* b2     = (const float*)d_in[7];
    const int* srcv = ei;
    const int* dstv = ei + N_EDGES;
    float* out = (float*)d_out;

    char* w = (char*)d_ws;
    size_t off = 0;
    auto alloc = [&](size_t bytes) {
        void* p = w + off;
        off = (off + bytes + 255) & ~(size_t)255;
        return p;
    };
    int*   deg     = (int*)alloc(N_NODES * 4);
    float* dis     = (float*)alloc(N_NODES * 4);
    int*   rs      = (int*)alloc((N_NODES + 1) * 4);
    int*   cur     = (int*)alloc(N_NODES * 4);
    int*   partial = (int*)alloc(128 * 4);
    int*   poff    = (int*)alloc(128 * 4);
    float* bnsum   = (float*)alloc(256 * 4);
    float* bnsq    = (float*)alloc(256 * 4);
    float* a_c     = (float*)alloc(256 * 4);
    float* b_c     = (float*)alloc(256 * 4);
    int*   eidx    = (int*)alloc((size_t)N_EDGES * 4);
    unsigned short* g1 = (unsigned short*)alloc((size_t)N_NODES * C_HID * 2);
    unsigned short* z1 = (unsigned short*)alloc((size_t)N_NODES * C_HID * 2);
    unsigned short* g2 = (unsigned short*)alloc((size_t)N_NODES * C_OUT * 2);
    (void)ws_size; (void)in_sizes; (void)n_in; (void)out_size;

    hipMemsetAsync(deg, 0, N_NODES * 4, stream);
    hipMemsetAsync(bnsum, 0, 2048, stream);  // bnsum + bnsq (contiguous 256B-aligned blocks)

    int nb = (N_NODES + 511) / 512;  // 98
    k_deg<<<(N_EDGES + 255) / 256, 256, 0, stream>>>(dstv, deg);
    k_dis<<<(N_NODES + 255) / 256, 256, 0, stream>>>(deg, dis);
    k_scan1<<<nb, 512, 0, stream>>>(deg, rs, partial);
    k_scan2<<<1, 64, 0, stream>>>(partial, poff, nb);
    k_scan3<<<(N_NODES + 255) / 256, 256, 0, stream>>>(rs, poff);
    k_cursor<<<(N_NODES + 255) / 256, 256, 0, stream>>>(rs, cur);
    k_scatter<<<(N_EDGES + 255) / 256, 256, 0, stream>>>(srcv, dstv, cur, eidx);

    dim3 gg1((N_NODES + BM - 1) / BM, C_HID / BN);
    k_gemm<false><<<gg1, 256, 0, stream>>>((const void*)x, W1, g1, dis, nullptr, nullptr, N_NODES, C_HID, C_IN);
    k_agg1<<<(N_NODES * 64 + 255) / 256, 256, 0, stream>>>(g1, dis, b1, rs, eidx, z1);
    k_bnstats<<<(N_NODES + 255) / 256, 256, 0, stream>>>(z1, bnsum, bnsq);
    k_bnfinal<<<1, 256, 0, stream>>>(bnsum, bnsq, gamma1, beta1, a_c, b_c);

    dim3 gg2((N_NODES + BM - 1) / BM, C_OUT / BN);
    k_gemm<true><<<gg2, 256, 0, stream>>>((const void*)z1, W2, g2, dis, a_c, b_c, N_NODES, C_OUT, C_HID);
    k_agg2<<<(N_NODES * 64 + 255) / 256, 256, 0, stream>>>(g2, dis, b2, rs, eidx, out);
}

// Round 3
// 451.753 us; speedup vs baseline: 1.1730x; 1.0486x over previous
//
#include <hip/hip_runtime.h>

#define N_NODES 50000
#define N_EDGES 800000
#define C_IN 128
#define C_HID 256
#define C_OUT 128
#define BN_EPS 1e-5f

// ---------- bf16 helpers (round-to-nearest-even) ----------
static __device__ __forceinline__ unsigned short f2bf(float f) {
    unsigned int u = __float_as_uint(f);
    u += 0x7fffu + ((u >> 16) & 1u);
    return (unsigned short)(u >> 16);
}
static __device__ __forceinline__ float bf2f(unsigned short h) {
    return __uint_as_float((unsigned int)h << 16);
}

// ---------------- degree ----------------

__global__ __launch_bounds__(256) void k_deg(const int* __restrict__ dst, int* __restrict__ deg) {
    int e = blockIdx.x * 256 + threadIdx.x;
    if (e < N_EDGES) atomicAdd(&deg[dst[e]], 1);
}

// ---------------- CSR build: scan + scatter ----------------
// k_scan1 also emits dis[i] = rsqrt(deg+1)  (fused former k_dis)

__global__ __launch_bounds__(512) void k_scan1(const int* __restrict__ deg, int* __restrict__ rs,
                                               int* __restrict__ partial, float* __restrict__ dis) {
    __shared__ int s[512];
    int t = threadIdx.x;
    int i = blockIdx.x * 512 + t;
    int v = (i < N_NODES) ? deg[i] : 0;
    if (i < N_NODES) dis[i] = rsqrtf((float)v + 1.0f);
    s[t] = v;
    __syncthreads();
    for (int off = 1; off < 512; off <<= 1) {
        int tv = (t >= off) ? s[t - off] : 0;
        __syncthreads();
        s[t] += tv;
        __syncthreads();
    }
    if (i < N_NODES) rs[i + 1] = s[t];
    if (t == 511) partial[blockIdx.x] = s[511];
}

// parallel scan over <=128 block partials (was a serial single-thread loop)
__global__ __launch_bounds__(128) void k_scan2(const int* __restrict__ partial, int* __restrict__ poff, int nb) {
    int t = threadIdx.x;
    int lane = t & 63;
    int pv = (t < nb) ? partial[t] : 0;
    int v = pv;
#pragma unroll
    for (int off = 1; off < 64; off <<= 1) {
        int u = __shfl_up(v, off);
        if (lane >= off) v += u;
    }
    __shared__ int wsum[2];
    if (lane == 63) wsum[t >> 6] = v;
    __syncthreads();
    if (t >= 64) v += wsum[0];
    if (t < nb) poff[t] = v - pv;  // exclusive
}

// adds block offsets; also writes cur[] = final row_start (fused former k_cursor)
__global__ __launch_bounds__(256) void k_scan3(int* __restrict__ rs, const int* __restrict__ poff,
                                               int* __restrict__ cur) {
    int i = blockIdx.x * 256 + threadIdx.x;
    if (i < N_NODES) {
        int v = rs[i + 1] + poff[i >> 9];
        rs[i + 1] = v;
        cur[i + 1] = v;
    }
    if (i == 0) { rs[0] = 0; cur[0] = 0; }
}

__global__ __launch_bounds__(256) void k_scatter(const int* __restrict__ src, const int* __restrict__ dst,
                                                 int* __restrict__ cur, int* __restrict__ eidx) {
    int e = blockIdx.x * 256 + threadIdx.x;
    if (e < N_EDGES) {
        int pos = atomicAdd(&cur[dst[e]], 1);
        eidx[pos] = src[e];
    }
}

// ---------------- tiled fp32 GEMM -> bf16 out: C[r][c] = bf16( (A@B)[r][c] * dis[r] ) ----
// TRANS: A is bf16 with fused BN+ReLU transform y = relu(a*tsc[k] + tof[k]).

#define BM 128
#define BN 64
#define BK 16

template <bool TRANS>
__global__ __launch_bounds__(256) void k_gemm(const void* __restrict__ Av, const float* __restrict__ B,
                                              unsigned short* __restrict__ C, const float* __restrict__ dis,
                                              const float* __restrict__ tsc, const float* __restrict__ tof,
                                              int M, int N, int K) {
    __shared__ float As[BK][BM + 4];
    __shared__ float Ws[BK][BN];
    int tid = threadIdx.x;
    int row0 = blockIdx.x * BM;
    int col0 = blockIdx.y * BN;
    int tx = tid & 15, ty = tid >> 4;
    int ar0 = tid >> 2;
    int acol4 = (tid & 3) * 4;
    int wrow = tid >> 4;
    int wcol4 = (tid & 15) * 4;
    float acc[8][4] = {};

    const float* Af = (const float*)Av;
    const unsigned short* Ah = (const unsigned short*)Av;

    for (int kt = 0; kt < K; kt += BK) {
        float a0[4] = {0.f, 0.f, 0.f, 0.f}, a1[4] = {0.f, 0.f, 0.f, 0.f};
        int r0 = row0 + ar0, r1 = row0 + ar0 + 64;
        if (TRANS) {
            float s4[4], o4[4];
            *(float4*)s4 = *(const float4*)&tsc[kt + acol4];
            *(float4*)o4 = *(const float4*)&tof[kt + acol4];
            if (r0 < M) {
                ushort4 h = *(const ushort4*)&Ah[(size_t)r0 * K + kt + acol4];
                a0[0] = fmaxf(fmaf(bf2f(h.x), s4[0], o4[0]), 0.f);
                a0[1] = fmaxf(fmaf(bf2f(h.y), s4[1], o4[1]), 0.f);
                a0[2] = fmaxf(fmaf(bf2f(h.z), s4[2], o4[2]), 0.f);
                a0[3] = fmaxf(fmaf(bf2f(h.w), s4[3], o4[3]), 0.f);
            }
            if (r1 < M) {
                ushort4 h = *(const ushort4*)&Ah[(size_t)r1 * K + kt + acol4];
                a1[0] = fmaxf(fmaf(bf2f(h.x), s4[0], o4[0]), 0.f);
                a1[1] = fmaxf(fmaf(bf2f(h.y), s4[1], o4[1]), 0.f);
                a1[2] = fmaxf(fmaf(bf2f(h.z), s4[2], o4[2]), 0.f);
                a1[3] = fmaxf(fmaf(bf2f(h.w), s4[3], o4[3]), 0.f);
            }
        } else {
            if (r0 < M) *(float4*)a0 = *(const float4*)&Af[(size_t)r0 * K + kt + acol4];
            if (r1 < M) *(float4*)a1 = *(const float4*)&Af[(size_t)r1 * K + kt + acol4];
        }
        float4 wv = *(const float4*)&B[(size_t)(kt + wrow) * N + col0 + wcol4];
        __syncthreads();
        As[acol4 + 0][ar0] = a0[0];
        As[acol4 + 1][ar0] = a0[1];
        As[acol4 + 2][ar0] = a0[2];
        As[acol4 + 3][ar0] = a0[3];
        As[acol4 + 0][ar0 + 64] = a1[0];
        As[acol4 + 1][ar0 + 64] = a1[1];
        As[acol4 + 2][ar0 + 64] = a1[2];
        As[acol4 + 3][ar0 + 64] = a1[3];
        *(float4*)&Ws[wrow][wcol4] = wv;
        __syncthreads();
#pragma unroll
        for (int k = 0; k < BK; ++k) {
            float ar[8], br[4];
            *(float4*)&ar[0] = *(const float4*)&As[k][ty * 8];
            *(float4*)&ar[4] = *(const float4*)&As[k][ty * 8 + 4];
            *(float4*)&br[0] = *(const float4*)&Ws[k][tx * 4];
#pragma unroll
            for (int i = 0; i < 8; ++i)
#pragma unroll
                for (int j = 0; j < 4; ++j) acc[i][j] = fmaf(ar[i], br[j], acc[i][j]);
        }
    }
#pragma unroll
    for (int i = 0; i < 8; ++i) {
        int r = row0 + ty * 8 + i;
        if (r < M) {
            float d = dis[r];
            ushort4 o;
            o.x = f2bf(acc[i][0] * d);
            o.y = f2bf(acc[i][1] * d);
            o.z = f2bf(acc[i][2] * d);
            o.w = f2bf(acc[i][3] * d);
            *(ushort4*)&C[(size_t)r * N + col0 + tx * 4] = o;
        }
    }
}

// ---------------- aggregation: one wave per node, 4 gathers in flight ----------------
// z1[i] = bf16( dis[i] * (sum_{src->i} g1[src] + g1[i]) + b1 )   (256 ch: ushort4/lane)

__global__ __launch_bounds__(256) void k_agg1(const unsigned short* __restrict__ g1, const float* __restrict__ dis,
                                              const float* __restrict__ b1, const int* __restrict__ rs,
                                              const int* __restrict__ eidx, unsigned short* __restrict__ z1) {
    int wid = (blockIdx.x * 256 + threadIdx.x) >> 6;
    int lane = threadIdx.x & 63;
    if (wid >= N_NODES) return;
    int s = rs[wid], e = rs[wid + 1];
    float ax = 0.f, ay = 0.f, az = 0.f, aw = 0.f;
    int p = s;
    for (; p + 3 < e; p += 4) {  // 4 independent row gathers in flight (MLP)
        int s0 = eidx[p], s1 = eidx[p + 1], s2 = eidx[p + 2], s3 = eidx[p + 3];
        ushort4 v0 = *(const ushort4*)&g1[(size_t)s0 * C_HID + lane * 4];
        ushort4 v1 = *(const ushort4*)&g1[(size_t)s1 * C_HID + lane * 4];
        ushort4 v2 = *(const ushort4*)&g1[(size_t)s2 * C_HID + lane * 4];
        ushort4 v3 = *(const ushort4*)&g1[(size_t)s3 * C_HID + lane * 4];
        ax += (bf2f(v0.x) + bf2f(v1.x)) + (bf2f(v2.x) + bf2f(v3.x));
        ay += (bf2f(v0.y) + bf2f(v1.y)) + (bf2f(v2.y) + bf2f(v3.y));
        az += (bf2f(v0.z) + bf2f(v1.z)) + (bf2f(v2.z) + bf2f(v3.z));
        aw += (bf2f(v0.w) + bf2f(v1.w)) + (bf2f(v2.w) + bf2f(v3.w));
    }
    for (; p < e; ++p) {
        int s0 = eidx[p];
        ushort4 v0 = *(const ushort4*)&g1[(size_t)s0 * C_HID + lane * 4];
        ax += bf2f(v0.x); ay += bf2f(v0.y); az += bf2f(v0.z); aw += bf2f(v0.w);
    }
    ushort4 gi = *(const ushort4*)&g1[(size_t)wid * C_HID + lane * 4];
    float d = dis[wid];
    float4 bv = *(const float4*)&b1[lane * 4];
    ushort4 z;
    z.x = f2bf(fmaf(d, ax + bf2f(gi.x), bv.x));
    z.y = f2bf(fmaf(d, ay + bf2f(gi.y), bv.y));
    z.z = f2bf(fmaf(d, az + bf2f(gi.z), bv.z));
    z.w = f2bf(fmaf(d, aw + bf2f(gi.w), bv.w));
    *(ushort4*)&z1[(size_t)wid * C_HID + lane * 4] = z;
}

// out[i] = dis[i] * (sum g2[src] + g2[i]) + b2   (128 ch: ushort2/lane, fp32 out)
__global__ __launch_bounds__(256) void k_agg2(const unsigned short* __restrict__ g2, const float* __restrict__ dis,
                                              const float* __restrict__ b2, const int* __restrict__ rs,
                                              const int* __restrict__ eidx, float* __restrict__ out) {
    int wid = (blockIdx.x * 256 + threadIdx.x) >> 6;
    int lane = threadIdx.x & 63;
    if (wid >= N_NODES) return;
    int s = rs[wid], e = rs[wid + 1];
    float ax = 0.f, ay = 0.f, bx = 0.f, by = 0.f;
    int p = s;
    for (; p + 7 < e; p += 8) {  // 8 gathers (256B rows) in flight
        int s0 = eidx[p], s1 = eidx[p + 1], s2 = eidx[p + 2], s3 = eidx[p + 3];
        int s4 = eidx[p + 4], s5 = eidx[p + 5], s6 = eidx[p + 6], s7 = eidx[p + 7];
        ushort2 v0 = *(const ushort2*)&g2[(size_t)s0 * C_OUT + lane * 2];
        ushort2 v1 = *(const ushort2*)&g2[(size_t)s1 * C_OUT + lane * 2];
        ushort2 v2 = *(const ushort2*)&g2[(size_t)s2 * C_OUT + lane * 2];
        ushort2 v3 = *(const ushort2*)&g2[(size_t)s3 * C_OUT + lane * 2];
        ushort2 v4 = *(const ushort2*)&g2[(size_t)s4 * C_OUT + lane * 2];
        ushort2 v5 = *(const ushort2*)&g2[(size_t)s5 * C_OUT + lane * 2];
        ushort2 v6 = *(const ushort2*)&g2[(size_t)s6 * C_OUT + lane * 2];
        ushort2 v7 = *(const ushort2*)&g2[(size_t)s7 * C_OUT + lane * 2];
        ax += (bf2f(v0.x) + bf2f(v1.x)) + (bf2f(v2.x) + bf2f(v3.x));
        ay += (bf2f(v0.y) + bf2f(v1.y)) + (bf2f(v2.y) + bf2f(v3.y));
        bx += (bf2f(v4.x) + bf2f(v5.x)) + (bf2f(v6.x) + bf2f(v7.x));
        by += (bf2f(v4.y) + bf2f(v5.y)) + (bf2f(v6.y) + bf2f(v7.y));
    }
    for (; p < e; ++p) {
        int s0 = eidx[p];
        ushort2 v0 = *(const ushort2*)&g2[(size_t)s0 * C_OUT + lane * 2];
        ax += bf2f(v0.x); ay += bf2f(v0.y);
    }
    ax += bx; ay += by;
    ushort2 gi = *(const ushort2*)&g2[(size_t)wid * C_OUT + lane * 2];
    float d = dis[wid];
    float2 bv = *(const float2*)&b2[lane * 2];
    float2 o = make_float2(fmaf(d, ax + bf2f(gi.x), bv.x), fmaf(d, ay + bf2f(gi.y), bv.y));
    *(float2*)&out[(size_t)wid * C_OUT + lane * 2] = o;
}

// ---------------- BN stats (from bf16 z1) ----------------

__global__ __launch_bounds__(256) void k_bnstats(const unsigned short* __restrict__ z1, float* __restrict__ bnsum,
                                                 float* __restrict__ bnsq) {
    int c = threadIdx.x;
    int r0 = blockIdx.x * 256;
    int r1 = r0 + 256 < N_NODES ? r0 + 256 : N_NODES;
    float sum = 0.f, sq = 0.f;
    for (int r = r0; r < r1; ++r) {
        float v = bf2f(z1[(size_t)r * C_HID + c]);
        sum += v;
        sq = fmaf(v, v, sq);
    }
    atomicAdd(&bnsum[c], sum);
    atomicAdd(&bnsq[c], sq);
}

__global__ void k_bnfinal(const float* __restrict__ bnsum, const float* __restrict__ bnsq,
                          const float* __restrict__ gamma, const float* __restrict__ beta,
                          float* __restrict__ a_c, float* __restrict__ b_c) {
    int c = threadIdx.x;
    float inv_n = 1.0f / (float)N_NODES;
    float mu = bnsum[c] * inv_n;
    float var = bnsq[c] * inv_n - mu * mu;
    float a = gamma[c] * rsqrtf(var + BN_EPS);
    a_c[c] = a;
    b_c[c] = beta[c] - mu * a;
}

// ---------------- launch ----------------

extern "C" void kernel_launch(void* const* d_in, const int* in_sizes, int n_in,
                              void* d_out, int out_size, void* d_ws, size_t ws_size,
                              hipStream_t stream) {
    const float* x      = (const float*)d_in[0];
    const int*   ei     = (const int*)d_in[1];
    const float* W1     = (const float*)d_in[2];
    const float* b1     = (const float*)d_in[3];
    const float* gamma1 = (const float*)d_in[4];
    const float* beta1  = (const float*)d_in[5];
    const float* W2     = (const float*)d_in[6];
    const float* b2     = (const float*)d_in[7];
    const int* srcv = ei;
    const int* dstv = ei + N_EDGES;
    float* out = (float*)d_out;

    char* w = (char*)d_ws;
    size_t off = 0;
    auto alloc = [&](size_t bytes) {
        void* p = w + off;
        off = (off + bytes + 255) & ~(size_t)255;
        return p;
    };
    int*   deg     = (int*)alloc(N_NODES * 4);
    float* dis     = (float*)alloc(N_NODES * 4);
    int*   rs      = (int*)alloc((N_NODES + 1) * 4);
    int*   cur     = (int*)alloc((N_NODES + 1) * 4);
    int*   partial = (int*)alloc(128 * 4);
    int*   poff    = (int*)alloc(128 * 4);
    float* bnsum   = (float*)alloc(256 * 4);
    float* bnsq    = (float*)alloc(256 * 4);
    float* a_c     = (float*)alloc(256 * 4);
    float* b_c     = (float*)alloc(256 * 4);
    int*   eidx    = (int*)alloc((size_t)N_EDGES * 4);
    unsigned short* g1 = (unsigned short*)alloc((size_t)N_NODES * C_HID * 2);
    unsigned short* z1 = (unsigned short*)alloc((size_t)N_NODES * C_HID * 2);
    unsigned short* g2 = (unsigned short*)alloc((size_t)N_NODES * C_OUT * 2);
    (void)ws_size; (void)in_sizes; (void)n_in; (void)out_size;

    hipMemsetAsync(deg, 0, N_NODES * 4, stream);
    hipMemsetAsync(bnsum, 0, 2048, stream);  // bnsum + bnsq (contiguous 256B-aligned blocks)

    int nb = (N_NODES + 511) / 512;  // 98
    k_deg<<<(N_EDGES + 255) / 256, 256, 0, stream>>>(dstv, deg);
    k_scan1<<<nb, 512, 0, stream>>>(deg, rs, partial, dis);
    k_scan2<<<1, 128, 0, stream>>>(partial, poff, nb);
    k_scan3<<<(N_NODES + 255) / 256, 256, 0, stream>>>(rs, poff, cur);
    k_scatter<<<(N_EDGES + 255) / 256, 256, 0, stream>>>(srcv, dstv, cur, eidx);

    dim3 gg1((N_NODES + BM - 1) / BM, C_HID / BN);
    k_gemm<false><<<gg1, 256, 0, stream>>>((const void*)x, W1, g1, dis, nullptr, nullptr, N_NODES, C_HID, C_IN);
    k_agg1<<<(N_NODES * 64 + 255) / 256, 256, 0, stream>>>(g1, dis, b1, rs, eidx, z1);
    k_bnstats<<<(N_NODES + 255) / 256, 256, 0, stream>>>(z1, bnsum, bnsq);
    k_bnfinal<<<1, 256, 0, stream>>>(bnsum, bnsq, gamma1, beta1, a_c, b_c);

    dim3 gg2((N_NODES + BM - 1) / BM, C_OUT / BN);
    k_gemm<true><<<gg2, 256, 0, stream>>>((const void*)z1, W2, g2, dis, a_c, b_c, N_NODES, C_OUT, C_HID);
    k_agg2<<<(N_NODES * 64 + 255) / 256, 256, 0, stream>>>(g2, dis, b2, rs, eidx, out);
}

// Round 4
// 400.532 us; speedup vs baseline: 1.3230x; 1.1279x over previous
//
#include <hip/hip_runtime.h>

#define N_NODES 50000
#define N_EDGES 800000
#define C_IN 128
#define C_HID 256
#define C_OUT 128
#define BN_EPS 1e-5f

typedef __bf16 v8bf __attribute__((ext_vector_type(8)));
typedef float f32x4 __attribute__((ext_vector_type(4)));

// ---------- bf16 helpers (round-to-nearest-even) ----------
static __device__ __forceinline__ unsigned short f2bf(float f) {
    unsigned int u = __float_as_uint(f);
    u += 0x7fffu + ((u >> 16) & 1u);
    return (unsigned short)(u >> 16);
}
static __device__ __forceinline__ float bf2f(unsigned short h) {
    return __uint_as_float((unsigned int)h << 16);
}
static __device__ __forceinline__ unsigned int pack2(float a, float b) {
    return (unsigned int)f2bf(a) | ((unsigned int)f2bf(b) << 16);
}
static __device__ __forceinline__ float lo2f(unsigned int u) { return __uint_as_float(u << 16); }
static __device__ __forceinline__ float hi2f(unsigned int u) { return __uint_as_float(u & 0xffff0000u); }

// ---------------- degree ----------------

__global__ __launch_bounds__(256) void k_deg(const int* __restrict__ dst, int* __restrict__ deg) {
    int e = blockIdx.x * 256 + threadIdx.x;
    if (e < N_EDGES) atomicAdd(&deg[dst[e]], 1);
}

// ---------------- CSR build: scan + scatter ----------------

__global__ __launch_bounds__(512) void k_scan1(const int* __restrict__ deg, int* __restrict__ rs,
                                               int* __restrict__ partial, float* __restrict__ dis) {
    __shared__ int s[512];
    int t = threadIdx.x;
    int i = blockIdx.x * 512 + t;
    int v = (i < N_NODES) ? deg[i] : 0;
    if (i < N_NODES) dis[i] = rsqrtf((float)v + 1.0f);
    s[t] = v;
    __syncthreads();
    for (int off = 1; off < 512; off <<= 1) {
        int tv = (t >= off) ? s[t - off] : 0;
        __syncthreads();
        s[t] += tv;
        __syncthreads();
    }
    if (i < N_NODES) rs[i + 1] = s[t];
    if (t == 511) partial[blockIdx.x] = s[511];
}

__global__ __launch_bounds__(128) void k_scan2(const int* __restrict__ partial, int* __restrict__ poff, int nb) {
    int t = threadIdx.x;
    int lane = t & 63;
    int pv = (t < nb) ? partial[t] : 0;
    int v = pv;
#pragma unroll
    for (int off = 1; off < 64; off <<= 1) {
        int u = __shfl_up(v, off);
        if (lane >= off) v += u;
    }
    __shared__ int wsum[2];
    if (lane == 63) wsum[t >> 6] = v;
    __syncthreads();
    if (t >= 64) v += wsum[0];
    if (t < nb) poff[t] = v - pv;  // exclusive
}

__global__ __launch_bounds__(256) void k_scan3(int* __restrict__ rs, const int* __restrict__ poff,
                                               int* __restrict__ cur) {
    int i = blockIdx.x * 256 + threadIdx.x;
    if (i < N_NODES) {
        int v = rs[i + 1] + poff[i >> 9];
        rs[i + 1] = v;
        cur[i + 1] = v;
    }
    if (i == 0) { rs[0] = 0; cur[0] = 0; }
}

__global__ __launch_bounds__(256) void k_scatter(const int* __restrict__ src, const int* __restrict__ dst,
                                                 int* __restrict__ cur, int* __restrict__ eidx) {
    int e = blockIdx.x * 256 + threadIdx.x;
    if (e < N_EDGES) {
        int pos = atomicAdd(&cur[dst[e]], 1);
        eidx[pos] = src[e];
    }
}

// ---------------- weight transpose -> bf16 row-major [n][k] (B-fragment friendly) --------

__global__ __launch_bounds__(256) void k_wtrans(const float* __restrict__ W1, const float* __restrict__ W2,
                                                unsigned short* __restrict__ WT1, unsigned short* __restrict__ WT2) {
    int i = blockIdx.x * 256 + threadIdx.x;
    if (i < C_IN * C_HID) {                 // WT1[n][k] = W1[k][n], n<256, k<128
        int n = i / C_IN, k = i - n * C_IN;
        WT1[n * C_IN + k] = f2bf(W1[k * C_HID + n]);
    } else {
        int j = i - C_IN * C_HID;
        if (j < C_HID * C_OUT) {            // WT2[n][k] = W2[k][n], n<128, k<256
            int n = j / C_HID, k = j - n * C_HID;
            WT2[n * C_HID + k] = f2bf(W2[k * C_OUT + n]);
        }
    }
}

// ---------------- MFMA bf16 GEMM: C[r][c] = bf16( (A@B)[r][c] * dis[r] ) ----------------
// BM=128, BN=128, BK=64, 256 threads (4 waves), each wave 64x64 via 4x4 mfma_f32_16x16x32_bf16.
// A staged via VGPR with conversion: TRANS=false -> fp32 A cast bf16; TRANS=true -> bf16 A
// with fused BN+ReLU y=relu(a*tsc[k]+tof[k]). B = pre-transposed bf16 WT ([n][k] rows).
// LDS rows padded 64->72 bf16: fragment b128 reads are 2-way bank-aliased (free).

#define GBM 128
#define GBK 64
#define LDA 72

template <bool TRANS>
__global__ __launch_bounds__(256) void k_gemm(const void* __restrict__ Av, const unsigned short* __restrict__ BT,
                                              unsigned short* __restrict__ C, const float* __restrict__ dis,
                                              const float* __restrict__ tsc, const float* __restrict__ tof,
                                              int M, int N, int K) {
    __shared__ unsigned short Alds[GBM * LDA];
    __shared__ unsigned short Blds[GBM * LDA];
    __shared__ float dis_s[GBM];

    int t = threadIdx.x;
    int row0 = blockIdx.x * GBM;
    int col0 = blockIdx.y * GBM;
    int wave = t >> 6, lane = t & 63;
    int wm = wave & 1, wn = wave >> 1;
    int lm = lane & 15, quad = lane >> 4;

    if (t < GBM) dis_s[t] = (row0 + t < M) ? dis[row0 + t] : 0.f;

    const float* Af = (const float*)Av;
    const unsigned short* Ah = (const unsigned short*)Av;

    int sr = t >> 1;                 // staging row 0..127
    int kb = (t & 1) * 32;           // k sub-offset 0/32

    f32x4 acc[4][4] = {};

    for (int kt = 0; kt < K; kt += GBK) {
        uint4 sa[4], sb[4];
        int r = row0 + sr;
#pragma unroll
        for (int j = 0; j < 4; ++j) {
            int k = kt + kb + 8 * j;
            if (TRANS) {
                uint4 h = (r < M) ? *(const uint4*)&Ah[(size_t)r * K + k]
                                  : make_uint4(0u, 0u, 0u, 0u);
                float4 s0 = *(const float4*)&tsc[k];
                float4 s1 = *(const float4*)&tsc[k + 4];
                float4 o0 = *(const float4*)&tof[k];
                float4 o1 = *(const float4*)&tof[k + 4];
                float f0 = fmaxf(fmaf(lo2f(h.x), s0.x, o0.x), 0.f);
                float f1 = fmaxf(fmaf(hi2f(h.x), s0.y, o0.y), 0.f);
                float f2 = fmaxf(fmaf(lo2f(h.y), s0.z, o0.z), 0.f);
                float f3 = fmaxf(fmaf(hi2f(h.y), s0.w, o0.w), 0.f);
                float f4 = fmaxf(fmaf(lo2f(h.z), s1.x, o1.x), 0.f);
                float f5 = fmaxf(fmaf(hi2f(h.z), s1.y, o1.y), 0.f);
                float f6 = fmaxf(fmaf(lo2f(h.w), s1.z, o1.z), 0.f);
                float f7 = fmaxf(fmaf(hi2f(h.w), s1.w, o1.w), 0.f);
                sa[j] = make_uint4(pack2(f0, f1), pack2(f2, f3), pack2(f4, f5), pack2(f6, f7));
            } else {
                float4 v0 = make_float4(0.f, 0.f, 0.f, 0.f), v1 = v0;
                if (r < M) {
                    v0 = *(const float4*)&Af[(size_t)r * K + k];
                    v1 = *(const float4*)&Af[(size_t)r * K + k + 4];
                }
                sa[j] = make_uint4(pack2(v0.x, v0.y), pack2(v0.z, v0.w),
                                   pack2(v1.x, v1.y), pack2(v1.z, v1.w));
            }
            sb[j] = *(const uint4*)&BT[(size_t)(col0 + sr) * K + k];
        }
        __syncthreads();   // previous tile's fragment reads complete
#pragma unroll
        for (int j = 0; j < 4; ++j) {
            *(uint4*)&Alds[sr * LDA + kb + 8 * j] = sa[j];
            *(uint4*)&Blds[sr * LDA + kb + 8 * j] = sb[j];
        }
        __syncthreads();
#pragma unroll
        for (int kc = 0; kc < 2; ++kc) {
            v8bf af[4], bf[4];
#pragma unroll
            for (int im = 0; im < 4; ++im)
                af[im] = *(const v8bf*)&Alds[(wm * 64 + im * 16 + lm) * LDA + kc * 32 + quad * 8];
#pragma unroll
            for (int in = 0; in < 4; ++in)
                bf[in] = *(const v8bf*)&Blds[(wn * 64 + in * 16 + lm) * LDA + kc * 32 + quad * 8];
#pragma unroll
            for (int im = 0; im < 4; ++im)
#pragma unroll
                for (int in = 0; in < 4; ++in)
                    acc[im][in] = __builtin_amdgcn_mfma_f32_16x16x32_bf16(af[im], bf[in], acc[im][in], 0, 0, 0);
        }
    }
    // epilogue: C[row][col] = bf16(acc * dis[row]); C/D layout col=lane&15, row=quad*4+reg
#pragma unroll
    for (int im = 0; im < 4; ++im) {
        int rb = wm * 64 + im * 16 + quad * 4;
#pragma unroll
        for (int in = 0; in < 4; ++in) {
            f32x4 c = acc[im][in];
            int col = col0 + wn * 64 + in * 16 + lm;
#pragma unroll
            for (int q = 0; q < 4; ++q) {
                int row = row0 + rb + q;
                if (row < M) C[(size_t)row * N + col] = f2bf(c[q] * dis_s[rb + q]);
            }
        }
    }
}

// ---------------- aggregation: one wave per node, 4 gathers in flight ----------------

__global__ __launch_bounds__(256) void k_agg1(const unsigned short* __restrict__ g1, const float* __restrict__ dis,
                                              const float* __restrict__ b1, const int* __restrict__ rs,
                                              const int* __restrict__ eidx, unsigned short* __restrict__ z1) {
    int wid = (blockIdx.x * 256 + threadIdx.x) >> 6;
    int lane = threadIdx.x & 63;
    if (wid >= N_NODES) return;
    int s = rs[wid], e = rs[wid + 1];
    float ax = 0.f, ay = 0.f, az = 0.f, aw = 0.f;
    int p = s;
    for (; p + 3 < e; p += 4) {
        int s0 = eidx[p], s1 = eidx[p + 1], s2 = eidx[p + 2], s3 = eidx[p + 3];
        ushort4 v0 = *(const ushort4*)&g1[(size_t)s0 * C_HID + lane * 4];
        ushort4 v1 = *(const ushort4*)&g1[(size_t)s1 * C_HID + lane * 4];
        ushort4 v2 = *(const ushort4*)&g1[(size_t)s2 * C_HID + lane * 4];
        ushort4 v3 = *(const ushort4*)&g1[(size_t)s3 * C_HID + lane * 4];
        ax += (bf2f(v0.x) + bf2f(v1.x)) + (bf2f(v2.x) + bf2f(v3.x));
        ay += (bf2f(v0.y) + bf2f(v1.y)) + (bf2f(v2.y) + bf2f(v3.y));
        az += (bf2f(v0.z) + bf2f(v1.z)) + (bf2f(v2.z) + bf2f(v3.z));
        aw += (bf2f(v0.w) + bf2f(v1.w)) + (bf2f(v2.w) + bf2f(v3.w));
    }
    for (; p < e; ++p) {
        int s0 = eidx[p];
        ushort4 v0 = *(const ushort4*)&g1[(size_t)s0 * C_HID + lane * 4];
        ax += bf2f(v0.x); ay += bf2f(v0.y); az += bf2f(v0.z); aw += bf2f(v0.w);
    }
    ushort4 gi = *(const ushort4*)&g1[(size_t)wid * C_HID + lane * 4];
    float d = dis[wid];
    float4 bv = *(const float4*)&b1[lane * 4];
    ushort4 z;
    z.x = f2bf(fmaf(d, ax + bf2f(gi.x), bv.x));
    z.y = f2bf(fmaf(d, ay + bf2f(gi.y), bv.y));
    z.z = f2bf(fmaf(d, az + bf2f(gi.z), bv.z));
    z.w = f2bf(fmaf(d, aw + bf2f(gi.w), bv.w));
    *(ushort4*)&z1[(size_t)wid * C_HID + lane * 4] = z;
}

__global__ __launch_bounds__(256) void k_agg2(const unsigned short* __restrict__ g2, const float* __restrict__ dis,
                                              const float* __restrict__ b2, const int* __restrict__ rs,
                                              const int* __restrict__ eidx, float* __restrict__ out) {
    int wid = (blockIdx.x * 256 + threadIdx.x) >> 6;
    int lane = threadIdx.x & 63;
    if (wid >= N_NODES) return;
    int s = rs[wid], e = rs[wid + 1];
    float ax = 0.f, ay = 0.f, bx = 0.f, by = 0.f;
    int p = s;
    for (; p + 7 < e; p += 8) {
        int s0 = eidx[p], s1 = eidx[p + 1], s2 = eidx[p + 2], s3 = eidx[p + 3];
        int s4 = eidx[p + 4], s5 = eidx[p + 5], s6 = eidx[p + 6], s7 = eidx[p + 7];
        ushort2 v0 = *(const ushort2*)&g2[(size_t)s0 * C_OUT + lane * 2];
        ushort2 v1 = *(const ushort2*)&g2[(size_t)s1 * C_OUT + lane * 2];
        ushort2 v2 = *(const ushort2*)&g2[(size_t)s2 * C_OUT + lane * 2];
        ushort2 v3 = *(const ushort2*)&g2[(size_t)s3 * C_OUT + lane * 2];
        ushort2 v4 = *(const ushort2*)&g2[(size_t)s4 * C_OUT + lane * 2];
        ushort2 v5 = *(const ushort2*)&g2[(size_t)s5 * C_OUT + lane * 2];
        ushort2 v6 = *(const ushort2*)&g2[(size_t)s6 * C_OUT + lane * 2];
        ushort2 v7 = *(const ushort2*)&g2[(size_t)s7 * C_OUT + lane * 2];
        ax += (bf2f(v0.x) + bf2f(v1.x)) + (bf2f(v2.x) + bf2f(v3.x));
        ay += (bf2f(v0.y) + bf2f(v1.y)) + (bf2f(v2.y) + bf2f(v3.y));
        bx += (bf2f(v4.x) + bf2f(v5.x)) + (bf2f(v6.x) + bf2f(v7.x));
        by += (bf2f(v4.y) + bf2f(v5.y)) + (bf2f(v6.y) + bf2f(v7.y));
    }
    for (; p < e; ++p) {
        int s0 = eidx[p];
        ushort2 v0 = *(const ushort2*)&g2[(size_t)s0 * C_OUT + lane * 2];
        ax += bf2f(v0.x); ay += bf2f(v0.y);
    }
    ax += bx; ay += by;
    ushort2 gi = *(const ushort2*)&g2[(size_t)wid * C_OUT + lane * 2];
    float d = dis[wid];
    float2 bv = *(const float2*)&b2[lane * 2];
    float2 o = make_float2(fmaf(d, ax + bf2f(gi.x), bv.x), fmaf(d, ay + bf2f(gi.y), bv.y));
    *(float2*)&out[(size_t)wid * C_OUT + lane * 2] = o;
}

// ---------------- BN stats (from bf16 z1) ----------------

__global__ __launch_bounds__(256) void k_bnstats(const unsigned short* __restrict__ z1, float* __restrict__ bnsum,
                                                 float* __restrict__ bnsq) {
    int c = threadIdx.x;
    int r0 = blockIdx.x * 256;
    int r1 = r0 + 256 < N_NODES ? r0 + 256 : N_NODES;
    float sum = 0.f, sq = 0.f;
    for (int r = r0; r < r1; ++r) {
        float v = bf2f(z1[(size_t)r * C_HID + c]);
        sum += v;
        sq = fmaf(v, v, sq);
    }
    atomicAdd(&bnsum[c], sum);
    atomicAdd(&bnsq[c], sq);
}

__global__ void k_bnfinal(const float* __restrict__ bnsum, const float* __restrict__ bnsq,
                          const float* __restrict__ gamma, const float* __restrict__ beta,
                          float* __restrict__ a_c, float* __restrict__ b_c) {
    int c = threadIdx.x;
    float inv_n = 1.0f / (float)N_NODES;
    float mu = bnsum[c] * inv_n;
    float var = bnsq[c] * inv_n - mu * mu;
    float a = gamma[c] * rsqrtf(var + BN_EPS);
    a_c[c] = a;
    b_c[c] = beta[c] - mu * a;
}

// ---------------- launch ----------------

extern "C" void kernel_launch(void* const* d_in, const int* in_sizes, int n_in,
                              void* d_out, int out_size, void* d_ws, size_t ws_size,
                              hipStream_t stream) {
    const float* x      = (const float*)d_in[0];
    const int*   ei     = (const int*)d_in[1];
    const float* W1     = (const float*)d_in[2];
    const float* b1     = (const float*)d_in[3];
    const float* gamma1 = (const float*)d_in[4];
    const float* beta1  = (const float*)d_in[5];
    const float* W2     = (const float*)d_in[6];
    const float* b2     = (const float*)d_in[7];
    const int* srcv = ei;
    const int* dstv = ei + N_EDGES;
    float* out = (float*)d_out;

    char* w = (char*)d_ws;
    size_t off = 0;
    auto alloc = [&](size_t bytes) {
        void* p = w + off;
        off = (off + bytes + 255) & ~(size_t)255;
        return p;
    };
    int*   deg     = (int*)alloc(N_NODES * 4);
    float* dis     = (float*)alloc(N_NODES * 4);
    int*   rs      = (int*)alloc((N_NODES + 1) * 4);
    int*   cur     = (int*)alloc((N_NODES + 1) * 4);
    int*   partial = (int*)alloc(128 * 4);
    int*   poff    = (int*)alloc(128 * 4);
    float* bnsum   = (float*)alloc(256 * 4);
    float* bnsq    = (float*)alloc(256 * 4);
    float* a_c     = (float*)alloc(256 * 4);
    float* b_c     = (float*)alloc(256 * 4);
    int*   eidx    = (int*)alloc((size_t)N_EDGES * 4);
    unsigned short* WT1 = (unsigned short*)alloc((size_t)C_IN * C_HID * 2);
    unsigned short* WT2 = (unsigned short*)alloc((size_t)C_HID * C_OUT * 2);
    unsigned short* g1 = (unsigned short*)alloc((size_t)N_NODES * C_HID * 2);
    unsigned short* z1 = (unsigned short*)alloc((size_t)N_NODES * C_HID * 2);
    unsigned short* g2 = (unsigned short*)alloc((size_t)N_NODES * C_OUT * 2);
    (void)ws_size; (void)in_sizes; (void)n_in; (void)out_size;

    hipMemsetAsync(deg, 0, N_NODES * 4, stream);
    hipMemsetAsync(bnsum, 0, 2048, stream);

    int nb = (N_NODES + 511) / 512;  // 98
    k_deg<<<(N_EDGES + 255) / 256, 256, 0, stream>>>(dstv, deg);
    k_scan1<<<nb, 512, 0, stream>>>(deg, rs, partial, dis);
    k_scan2<<<1, 128, 0, stream>>>(partial, poff, nb);
    k_scan3<<<(N_NODES + 255) / 256, 256, 0, stream>>>(rs, poff, cur);
    k_scatter<<<(N_EDGES + 255) / 256, 256, 0, stream>>>(srcv, dstv, cur, eidx);
    k_wtrans<<<(C_IN * C_HID + C_HID * C_OUT + 255) / 256, 256, 0, stream>>>(W1, W2, WT1, WT2);

    dim3 gg1((N_NODES + GBM - 1) / GBM, C_HID / GBM);
    k_gemm<false><<<gg1, 256, 0, stream>>>((const void*)x, WT1, g1, dis, nullptr, nullptr,
                                           N_NODES, C_HID, C_IN);
    k_agg1<<<(N_NODES * 64 + 255) / 256, 256, 0, stream>>>(g1, dis, b1, rs, eidx, z1);
    k_bnstats<<<(N_NODES + 255) / 256, 256, 0, stream>>>(z1, bnsum, bnsq);
    k_bnfinal<<<1, 256, 0, stream>>>(bnsum, bnsq, gamma1, beta1, a_c, b_c);

    dim3 gg2((N_NODES + GBM - 1) / GBM, C_OUT / GBM);
    k_gemm<true><<<gg2, 256, 0, stream>>>((const void*)z1, WT2, g2, dis, a_c, b_c,
                                          N_NODES, C_OUT, C_HID);
    k_agg2<<<(N_NODES * 64 + 255) / 256, 256, 0, stream>>>(g2, dis, b2, rs, eidx, out);
}

// Round 5
// 346.723 us; speedup vs baseline: 1.5284x; 1.1552x over previous
//
#include <hip/hip_runtime.h>

#define N_NODES 50000
#define N_EDGES 800000
#define C_IN 128
#define C_HID 256
#define C_OUT 128
#define BN_EPS 1e-5f

typedef __bf16 v8bf __attribute__((ext_vector_type(8)));
typedef float f32x4 __attribute__((ext_vector_type(4)));

// ---------- bf16 helpers (round-to-nearest-even) ----------
static __device__ __forceinline__ unsigned short f2bf(float f) {
    unsigned int u = __float_as_uint(f);
    u += 0x7fffu + ((u >> 16) & 1u);
    return (unsigned short)(u >> 16);
}
static __device__ __forceinline__ float bf2f(unsigned short h) {
    return __uint_as_float((unsigned int)h << 16);
}
static __device__ __forceinline__ unsigned int pack2(float a, float b) {
    return (unsigned int)f2bf(a) | ((unsigned int)f2bf(b) << 16);
}
static __device__ __forceinline__ float lo2f(unsigned int u) { return __uint_as_float(u << 16); }
static __device__ __forceinline__ float hi2f(unsigned int u) { return __uint_as_float(u & 0xffff0000u); }

// ---------------- degree ----------------

__global__ __launch_bounds__(256) void k_deg(const int* __restrict__ dst, int* __restrict__ deg) {
    int e = blockIdx.x * 256 + threadIdx.x;
    if (e < N_EDGES) atomicAdd(&deg[dst[e]], 1);
}

// ---------------- CSR build: scan + scatter ----------------

__global__ __launch_bounds__(512) void k_scan1(const int* __restrict__ deg, int* __restrict__ rs,
                                               int* __restrict__ partial, float* __restrict__ dis) {
    __shared__ int s[512];
    int t = threadIdx.x;
    int i = blockIdx.x * 512 + t;
    int v = (i < N_NODES) ? deg[i] : 0;
    if (i < N_NODES) dis[i] = rsqrtf((float)v + 1.0f);
    s[t] = v;
    __syncthreads();
    for (int off = 1; off < 512; off <<= 1) {
        int tv = (t >= off) ? s[t - off] : 0;
        __syncthreads();
        s[t] += tv;
        __syncthreads();
    }
    if (i < N_NODES) rs[i + 1] = s[t];
    if (t == 511) partial[blockIdx.x] = s[511];
}

__global__ __launch_bounds__(128) void k_scan2(const int* __restrict__ partial, int* __restrict__ poff, int nb) {
    int t = threadIdx.x;
    int lane = t & 63;
    int pv = (t < nb) ? partial[t] : 0;
    int v = pv;
#pragma unroll
    for (int off = 1; off < 64; off <<= 1) {
        int u = __shfl_up(v, off);
        if (lane >= off) v += u;
    }
    __shared__ int wsum[2];
    if (lane == 63) wsum[t >> 6] = v;
    __syncthreads();
    if (t >= 64) v += wsum[0];
    if (t < nb) poff[t] = v - pv;  // exclusive
}

__global__ __launch_bounds__(256) void k_scan3(int* __restrict__ rs, const int* __restrict__ poff,
                                               int* __restrict__ cur) {
    int i = blockIdx.x * 256 + threadIdx.x;
    if (i < N_NODES) {
        int v = rs[i + 1] + poff[i >> 9];
        rs[i + 1] = v;
        cur[i + 1] = v;
    }
    if (i == 0) { rs[0] = 0; cur[0] = 0; }
}

__global__ __launch_bounds__(256) void k_scatter(const int* __restrict__ src, const int* __restrict__ dst,
                                                 int* __restrict__ cur, int* __restrict__ eidx) {
    int e = blockIdx.x * 256 + threadIdx.x;
    if (e < N_EDGES) {
        int pos = atomicAdd(&cur[dst[e]], 1);
        eidx[pos] = src[e];
    }
}

// ---------------- weight transpose -> bf16 row-major [n][k] ----------------

__global__ __launch_bounds__(256) void k_wtrans(const float* __restrict__ W1, const float* __restrict__ W2,
                                                unsigned short* __restrict__ WT1, unsigned short* __restrict__ WT2) {
    int i = blockIdx.x * 256 + threadIdx.x;
    if (i < C_IN * C_HID) {                 // WT1[n][k] = W1[k][n]
        int n = i / C_IN, k = i - n * C_IN;
        WT1[n * C_IN + k] = f2bf(W1[k * C_HID + n]);
    } else {
        int j = i - C_IN * C_HID;
        if (j < C_HID * C_OUT) {            // WT2[n][k] = W2[k][n]
            int n = j / C_HID, k = j - n * C_HID;
            WT2[n * C_HID + k] = f2bf(W2[k * C_OUT + n]);
        }
    }
}

// ---------------- MFMA bf16 GEMM: C[r][c] = bf16( (A@B)[r][c] * dis[r] ) ----------------

#define GBM 128
#define GBK 64
#define LDA 72

template <bool TRANS>
__global__ __launch_bounds__(256) void k_gemm(const void* __restrict__ Av, const unsigned short* __restrict__ BT,
                                              unsigned short* __restrict__ C, const float* __restrict__ dis,
                                              const float* __restrict__ tsc, const float* __restrict__ tof,
                                              int M, int N, int K) {
    __shared__ unsigned short Alds[GBM * LDA];
    __shared__ unsigned short Blds[GBM * LDA];
    __shared__ float dis_s[GBM];

    int t = threadIdx.x;
    int row0 = blockIdx.x * GBM;
    int col0 = blockIdx.y * GBM;
    int wave = t >> 6, lane = t & 63;
    int wm = wave & 1, wn = wave >> 1;
    int lm = lane & 15, quad = lane >> 4;

    if (t < GBM) dis_s[t] = (row0 + t < M) ? dis[row0 + t] : 0.f;

    const float* Af = (const float*)Av;
    const unsigned short* Ah = (const unsigned short*)Av;

    int sr = t >> 1;
    int kb = (t & 1) * 32;

    f32x4 acc[4][4] = {};

    for (int kt = 0; kt < K; kt += GBK) {
        uint4 sa[4], sb[4];
        int r = row0 + sr;
#pragma unroll
        for (int j = 0; j < 4; ++j) {
            int k = kt + kb + 8 * j;
            if (TRANS) {
                uint4 h = (r < M) ? *(const uint4*)&Ah[(size_t)r * K + k]
                                  : make_uint4(0u, 0u, 0u, 0u);
                float4 s0 = *(const float4*)&tsc[k];
                float4 s1 = *(const float4*)&tsc[k + 4];
                float4 o0 = *(const float4*)&tof[k];
                float4 o1 = *(const float4*)&tof[k + 4];
                float f0 = fmaxf(fmaf(lo2f(h.x), s0.x, o0.x), 0.f);
                float f1 = fmaxf(fmaf(hi2f(h.x), s0.y, o0.y), 0.f);
                float f2 = fmaxf(fmaf(lo2f(h.y), s0.z, o0.z), 0.f);
                float f3 = fmaxf(fmaf(hi2f(h.y), s0.w, o0.w), 0.f);
                float f4 = fmaxf(fmaf(lo2f(h.z), s1.x, o1.x), 0.f);
                float f5 = fmaxf(fmaf(hi2f(h.z), s1.y, o1.y), 0.f);
                float f6 = fmaxf(fmaf(lo2f(h.w), s1.z, o1.z), 0.f);
                float f7 = fmaxf(fmaf(hi2f(h.w), s1.w, o1.w), 0.f);
                sa[j] = make_uint4(pack2(f0, f1), pack2(f2, f3), pack2(f4, f5), pack2(f6, f7));
            } else {
                float4 v0 = make_float4(0.f, 0.f, 0.f, 0.f), v1 = v0;
                if (r < M) {
                    v0 = *(const float4*)&Af[(size_t)r * K + k];
                    v1 = *(const float4*)&Af[(size_t)r * K + k + 4];
                }
                sa[j] = make_uint4(pack2(v0.x, v0.y), pack2(v0.z, v0.w),
                                   pack2(v1.x, v1.y), pack2(v1.z, v1.w));
            }
            sb[j] = *(const uint4*)&BT[(size_t)(col0 + sr) * K + k];
        }
        __syncthreads();
#pragma unroll
        for (int j = 0; j < 4; ++j) {
            *(uint4*)&Alds[sr * LDA + kb + 8 * j] = sa[j];
            *(uint4*)&Blds[sr * LDA + kb + 8 * j] = sb[j];
        }
        __syncthreads();
#pragma unroll
        for (int kc = 0; kc < 2; ++kc) {
            v8bf af[4], bfv[4];
#pragma unroll
            for (int im = 0; im < 4; ++im)
                af[im] = *(const v8bf*)&Alds[(wm * 64 + im * 16 + lm) * LDA + kc * 32 + quad * 8];
#pragma unroll
            for (int in = 0; in < 4; ++in)
                bfv[in] = *(const v8bf*)&Blds[(wn * 64 + in * 16 + lm) * LDA + kc * 32 + quad * 8];
#pragma unroll
            for (int im = 0; im < 4; ++im)
#pragma unroll
                for (int in = 0; in < 4; ++in)
                    acc[im][in] = __builtin_amdgcn_mfma_f32_16x16x32_bf16(af[im], bfv[in], acc[im][in], 0, 0, 0);
        }
    }
#pragma unroll
    for (int im = 0; im < 4; ++im) {
        int rb = wm * 64 + im * 16 + quad * 4;
#pragma unroll
        for (int in = 0; in < 4; ++in) {
            f32x4 c = acc[im][in];
            int col = col0 + wn * 64 + in * 16 + lm;
#pragma unroll
            for (int q = 0; q < 4; ++q) {
                int row = row0 + rb + q;
                if (row < M) C[(size_t)row * N + col] = f2bf(c[q] * dis_s[rb + q]);
            }
        }
    }
}

// ---------------- aggregation: one wave per node, 8 gathers in flight ----------------

__global__ __launch_bounds__(256) void k_agg1(const unsigned short* __restrict__ g1, const float* __restrict__ dis,
                                              const float* __restrict__ b1, const int* __restrict__ rs,
                                              const int* __restrict__ eidx, unsigned short* __restrict__ z1) {
    int wid = (blockIdx.x * 256 + threadIdx.x) >> 6;
    int lane = threadIdx.x & 63;
    if (wid >= N_NODES) return;
    int s = rs[wid], e = rs[wid + 1];
    float ax = 0.f, ay = 0.f, az = 0.f, aw = 0.f;
    float cx = 0.f, cy = 0.f, cz = 0.f, cw = 0.f;
    int p = s;
    for (; p + 7 < e; p += 8) {  // 8 independent row gathers in flight
        int s0 = eidx[p], s1 = eidx[p + 1], s2 = eidx[p + 2], s3 = eidx[p + 3];
        int s4 = eidx[p + 4], s5 = eidx[p + 5], s6 = eidx[p + 6], s7 = eidx[p + 7];
        ushort4 v0 = *(const ushort4*)&g1[(size_t)s0 * C_HID + lane * 4];
        ushort4 v1 = *(const ushort4*)&g1[(size_t)s1 * C_HID + lane * 4];
        ushort4 v2 = *(const ushort4*)&g1[(size_t)s2 * C_HID + lane * 4];
        ushort4 v3 = *(const ushort4*)&g1[(size_t)s3 * C_HID + lane * 4];
        ushort4 v4 = *(const ushort4*)&g1[(size_t)s4 * C_HID + lane * 4];
        ushort4 v5 = *(const ushort4*)&g1[(size_t)s5 * C_HID + lane * 4];
        ushort4 v6 = *(const ushort4*)&g1[(size_t)s6 * C_HID + lane * 4];
        ushort4 v7 = *(const ushort4*)&g1[(size_t)s7 * C_HID + lane * 4];
        ax += (bf2f(v0.x) + bf2f(v1.x)) + (bf2f(v2.x) + bf2f(v3.x));
        ay += (bf2f(v0.y) + bf2f(v1.y)) + (bf2f(v2.y) + bf2f(v3.y));
        az += (bf2f(v0.z) + bf2f(v1.z)) + (bf2f(v2.z) + bf2f(v3.z));
        aw += (bf2f(v0.w) + bf2f(v1.w)) + (bf2f(v2.w) + bf2f(v3.w));
        cx += (bf2f(v4.x) + bf2f(v5.x)) + (bf2f(v6.x) + bf2f(v7.x));
        cy += (bf2f(v4.y) + bf2f(v5.y)) + (bf2f(v6.y) + bf2f(v7.y));
        cz += (bf2f(v4.z) + bf2f(v5.z)) + (bf2f(v6.z) + bf2f(v7.z));
        cw += (bf2f(v4.w) + bf2f(v5.w)) + (bf2f(v6.w) + bf2f(v7.w));
    }
    for (; p + 1 < e; p += 2) {
        int s0 = eidx[p], s1 = eidx[p + 1];
        ushort4 v0 = *(const ushort4*)&g1[(size_t)s0 * C_HID + lane * 4];
        ushort4 v1 = *(const ushort4*)&g1[(size_t)s1 * C_HID + lane * 4];
        ax += bf2f(v0.x) + bf2f(v1.x); ay += bf2f(v0.y) + bf2f(v1.y);
        az += bf2f(v0.z) + bf2f(v1.z); aw += bf2f(v0.w) + bf2f(v1.w);
    }
    if (p < e) {
        int s0 = eidx[p];
        ushort4 v0 = *(const ushort4*)&g1[(size_t)s0 * C_HID + lane * 4];
        ax += bf2f(v0.x); ay += bf2f(v0.y); az += bf2f(v0.z); aw += bf2f(v0.w);
    }
    ax += cx; ay += cy; az += cz; aw += cw;
    ushort4 gi = *(const ushort4*)&g1[(size_t)wid * C_HID + lane * 4];
    float d = dis[wid];
    float4 bv = *(const float4*)&b1[lane * 4];
    ushort4 z;
    z.x = f2bf(fmaf(d, ax + bf2f(gi.x), bv.x));
    z.y = f2bf(fmaf(d, ay + bf2f(gi.y), bv.y));
    z.z = f2bf(fmaf(d, az + bf2f(gi.z), bv.z));
    z.w = f2bf(fmaf(d, aw + bf2f(gi.w), bv.w));
    *(ushort4*)&z1[(size_t)wid * C_HID + lane * 4] = z;
}

__global__ __launch_bounds__(256) void k_agg2(const unsigned short* __restrict__ g2, const float* __restrict__ dis,
                                              const float* __restrict__ b2, const int* __restrict__ rs,
                                              const int* __restrict__ eidx, float* __restrict__ out) {
    int wid = (blockIdx.x * 256 + threadIdx.x) >> 6;
    int lane = threadIdx.x & 63;
    if (wid >= N_NODES) return;
    int s = rs[wid], e = rs[wid + 1];
    float ax = 0.f, ay = 0.f, bx = 0.f, by = 0.f;
    int p = s;
    for (; p + 7 < e; p += 8) {
        int s0 = eidx[p], s1 = eidx[p + 1], s2 = eidx[p + 2], s3 = eidx[p + 3];
        int s4 = eidx[p + 4], s5 = eidx[p + 5], s6 = eidx[p + 6], s7 = eidx[p + 7];
        ushort2 v0 = *(const ushort2*)&g2[(size_t)s0 * C_OUT + lane * 2];
        ushort2 v1 = *(const ushort2*)&g2[(size_t)s1 * C_OUT + lane * 2];
        ushort2 v2 = *(const ushort2*)&g2[(size_t)s2 * C_OUT + lane * 2];
        ushort2 v3 = *(const ushort2*)&g2[(size_t)s3 * C_OUT + lane * 2];
        ushort2 v4 = *(const ushort2*)&g2[(size_t)s4 * C_OUT + lane * 2];
        ushort2 v5 = *(const ushort2*)&g2[(size_t)s5 * C_OUT + lane * 2];
        ushort2 v6 = *(const ushort2*)&g2[(size_t)s6 * C_OUT + lane * 2];
        ushort2 v7 = *(const ushort2*)&g2[(size_t)s7 * C_OUT + lane * 2];
        ax += (bf2f(v0.x) + bf2f(v1.x)) + (bf2f(v2.x) + bf2f(v3.x));
        ay += (bf2f(v0.y) + bf2f(v1.y)) + (bf2f(v2.y) + bf2f(v3.y));
        bx += (bf2f(v4.x) + bf2f(v5.x)) + (bf2f(v6.x) + bf2f(v7.x));
        by += (bf2f(v4.y) + bf2f(v5.y)) + (bf2f(v6.y) + bf2f(v7.y));
    }
    for (; p < e; ++p) {
        int s0 = eidx[p];
        ushort2 v0 = *(const ushort2*)&g2[(size_t)s0 * C_OUT + lane * 2];
        ax += bf2f(v0.x); ay += bf2f(v0.y);
    }
    ax += bx; ay += by;
    ushort2 gi = *(const ushort2*)&g2[(size_t)wid * C_OUT + lane * 2];
    float d = dis[wid];
    float2 bv = *(const float2*)&b2[lane * 2];
    float2 o = make_float2(fmaf(d, ax + bf2f(gi.x), bv.x), fmaf(d, ay + bf2f(gi.y), bv.y));
    *(float2*)&out[(size_t)wid * C_OUT + lane * 2] = o;
}

// ---------------- BN stats: one wave per row, vectorized, block-reduced ----------------
// wave lane holds channels c=lane*4..+3 via ushort4 (512B/row per wave); 2 row-streams in
// flight; 4 waves/block reduce via LDS; 512 global atomics per block.

#define BN_BLOCKS 256

__global__ __launch_bounds__(256) void k_bnstats(const unsigned short* __restrict__ z1, float* __restrict__ bnsum,
                                                 float* __restrict__ bnsq) {
    __shared__ float redsum[4][256];
    __shared__ float redsq[4][256];
    int t = threadIdx.x;
    int wave = t >> 6, lane = t & 63;
    int gw = blockIdx.x * 4 + wave;
    const int W = BN_BLOCKS * 4;
    float s0 = 0.f, s1 = 0.f, s2 = 0.f, s3 = 0.f;
    float q0 = 0.f, q1 = 0.f, q2 = 0.f, q3 = 0.f;
    int r = gw;
    for (; r + W < N_NODES; r += 2 * W) {  // two independent row streams
        ushort4 va = *(const ushort4*)&z1[(size_t)r * C_HID + lane * 4];
        ushort4 vb = *(const ushort4*)&z1[(size_t)(r + W) * C_HID + lane * 4];
        float a0 = bf2f(va.x), a1 = bf2f(va.y), a2 = bf2f(va.z), a3 = bf2f(va.w);
        float b0 = bf2f(vb.x), b1 = bf2f(vb.y), b2 = bf2f(vb.z), b3 = bf2f(vb.w);
        s0 += a0 + b0; s1 += a1 + b1; s2 += a2 + b2; s3 += a3 + b3;
        q0 = fmaf(a0, a0, fmaf(b0, b0, q0));
        q1 = fmaf(a1, a1, fmaf(b1, b1, q1));
        q2 = fmaf(a2, a2, fmaf(b2, b2, q2));
        q3 = fmaf(a3, a3, fmaf(b3, b3, q3));
    }
    if (r < N_NODES) {
        ushort4 va = *(const ushort4*)&z1[(size_t)r * C_HID + lane * 4];
        float a0 = bf2f(va.x), a1 = bf2f(va.y), a2 = bf2f(va.z), a3 = bf2f(va.w);
        s0 += a0; s1 += a1; s2 += a2; s3 += a3;
        q0 = fmaf(a0, a0, q0); q1 = fmaf(a1, a1, q1);
        q2 = fmaf(a2, a2, q2); q3 = fmaf(a3, a3, q3);
    }
    redsum[wave][lane * 4 + 0] = s0; redsum[wave][lane * 4 + 1] = s1;
    redsum[wave][lane * 4 + 2] = s2; redsum[wave][lane * 4 + 3] = s3;
    redsq[wave][lane * 4 + 0] = q0; redsq[wave][lane * 4 + 1] = q1;
    redsq[wave][lane * 4 + 2] = q2; redsq[wave][lane * 4 + 3] = q3;
    __syncthreads();
    float ts = redsum[0][t] + redsum[1][t] + redsum[2][t] + redsum[3][t];
    float tq = redsq[0][t] + redsq[1][t] + redsq[2][t] + redsq[3][t];
    atomicAdd(&bnsum[t], ts);
    atomicAdd(&bnsq[t], tq);
}

__global__ void k_bnfinal(const float* __restrict__ bnsum, const float* __restrict__ bnsq,
                          const float* __restrict__ gamma, const float* __restrict__ beta,
                          float* __restrict__ a_c, float* __restrict__ b_c) {
    int c = threadIdx.x;
    float inv_n = 1.0f / (float)N_NODES;
    float mu = bnsum[c] * inv_n;
    float var = bnsq[c] * inv_n - mu * mu;
    float a = gamma[c] * rsqrtf(var + BN_EPS);
    a_c[c] = a;
    b_c[c] = beta[c] - mu * a;
}

// ---------------- launch ----------------

extern "C" void kernel_launch(void* const* d_in, const int* in_sizes, int n_in,
                              void* d_out, int out_size, void* d_ws, size_t ws_size,
                              hipStream_t stream) {
    const float* x      = (const float*)d_in[0];
    const int*   ei     = (const int*)d_in[1];
    const float* W1     = (const float*)d_in[2];
    const float* b1     = (const float*)d_in[3];
    const float* gamma1 = (const float*)d_in[4];
    const float* beta1  = (const float*)d_in[5];
    const float* W2     = (const float*)d_in[6];
    const float* b2     = (const float*)d_in[7];
    const int* srcv = ei;
    const int* dstv = ei + N_EDGES;
    float* out = (float*)d_out;

    char* w = (char*)d_ws;
    size_t off = 0;
    auto alloc = [&](size_t bytes) {
        void* p = w + off;
        off = (off + bytes + 255) & ~(size_t)255;
        return p;
    };
    int*   deg     = (int*)alloc(N_NODES * 4);
    float* dis     = (float*)alloc(N_NODES * 4);
    int*   rs      = (int*)alloc((N_NODES + 1) * 4);
    int*   cur     = (int*)alloc((N_NODES + 1) * 4);
    int*   partial = (int*)alloc(128 * 4);
    int*   poff    = (int*)alloc(128 * 4);
    float* bnsum   = (float*)alloc(256 * 4);
    float* bnsq    = (float*)alloc(256 * 4);
    float* a_c     = (float*)alloc(256 * 4);
    float* b_c     = (float*)alloc(256 * 4);
    int*   eidx    = (int*)alloc((size_t)N_EDGES * 4);
    unsigned short* WT1 = (unsigned short*)alloc((size_t)C_IN * C_HID * 2);
    unsigned short* WT2 = (unsigned short*)alloc((size_t)C_HID * C_OUT * 2);
    unsigned short* g1 = (unsigned short*)alloc((size_t)N_NODES * C_HID * 2);
    unsigned short* z1 = (unsigned short*)alloc((size_t)N_NODES * C_HID * 2);
    unsigned short* g2 = (unsigned short*)alloc((size_t)N_NODES * C_OUT * 2);
    (void)ws_size; (void)in_sizes; (void)n_in; (void)out_size;

    hipMemsetAsync(deg, 0, N_NODES * 4, stream);
    hipMemsetAsync(bnsum, 0, 2048, stream);

    int nb = (N_NODES + 511) / 512;  // 98
    k_deg<<<(N_EDGES + 255) / 256, 256, 0, stream>>>(dstv, deg);
    k_scan1<<<nb, 512, 0, stream>>>(deg, rs, partial, dis);
    k_scan2<<<1, 128, 0, stream>>>(partial, poff, nb);
    k_scan3<<<(N_NODES + 255) / 256, 256, 0, stream>>>(rs, poff, cur);
    k_scatter<<<(N_EDGES + 255) / 256, 256, 0, stream>>>(srcv, dstv, cur, eidx);
    k_wtrans<<<(C_IN * C_HID + C_HID * C_OUT + 255) / 256, 256, 0, stream>>>(W1, W2, WT1, WT2);

    dim3 gg1((N_NODES + GBM - 1) / GBM, C_HID / GBM);
    k_gemm<false><<<gg1, 256, 0, stream>>>((const void*)x, WT1, g1, dis, nullptr, nullptr,
                                           N_NODES, C_HID, C_IN);
    k_agg1<<<(N_NODES * 64 + 255) / 256, 256, 0, stream>>>(g1, dis, b1, rs, eidx, z1);
    k_bnstats<<<BN_BLOCKS, 256, 0, stream>>>(z1, bnsum, bnsq);
    k_bnfinal<<<1, 256, 0, stream>>>(bnsum, bnsq, gamma1, beta1, a_c, b_c);

    dim3 gg2((N_NODES + GBM - 1) / GBM, C_OUT / GBM);
    k_gemm<true><<<gg2, 256, 0, stream>>>((const void*)z1, WT2, g2, dis, a_c, b_c,
                                          N_NODES, C_OUT, C_HID);
    k_agg2<<<(N_NODES * 64 + 255) / 256, 256, 0, stream>>>(g2, dis, b2, rs, eidx, out);
}